// Round 5
// baseline (110.043 us; speedup 1.0000x reference)
//
#include <hip/hip_runtime.h>
#include <math.h>

// Problem constants (from reference)
#define BB 4
#define HH 512
#define WW 512
#define CC 32      // channels; 32 floats = 8 float4 = 128 B per point
#define HO 256
#define WO 256

// Fill index grid with zeros (0 == empty). int4-vectorized.
__global__ void fill_zero_kernel(int4* __restrict__ g, int n4) {
    int i = blockIdx.x * blockDim.x + threadIdx.x;
    if (i < n4) g[i] = make_int4(0, 0, 0, 0);
}

// Scatter point index+1 into dense (B,H,W) int grid.
__global__ void scatter_idx_kernel(const int* __restrict__ coors,
                                   int* __restrict__ grid, int n) {
    int i = blockIdx.x * blockDim.x + threadIdx.x;
    if (i >= n) return;
    int b = coors[i * 3 + 0];
    int y = coors[i * 3 + 1];
    int x = coors[i * 3 + 2];
    grid[((size_t)b * HH + y) * WW + x] = i + 1;
}

// Block = 32 output-x positions x 2 output rows (oy=2t,2t+1) x 8 channel
// groups. Input window = 5 rows x 65 cols staged once through LDS.
// Each thread: 15 branchless float4 gathers in flight (shared middle row
// loaded once), two accumulators, two coalesced stores.
__global__ void __launch_bounds__(256)
pool_kernel(const float4* __restrict__ feat,   // N x 8 float4
            const int* __restrict__ grid,      // B*H*W
            float4* __restrict__ out) {        // B*HO*WO x 8 float4
    // blockIdx.x: [b(2b) | t(7b) | ox_tile(3b)],  t = oy pair index 0..127
    int ox_base = (blockIdx.x & 7) * 32;
    int t       = (blockIdx.x >> 3) & 127;
    int b       = blockIdx.x >> 10;

    int tid = threadIdx.x;
    int cg  = tid & 7;          // channel group 0..7
    int p   = tid >> 3;         // local position 0..31

    int iy0 = 4 * t - 1;        // first of 5 input rows
    int gx0 = 2 * ox_base - 1;
    const int* gb = grid + (size_t)b * (HH * WW);

    __shared__ int sg[5 * 66];  // 5 rows, pitch 66

    for (int e = tid; e < 5 * 65; e += 256) {
        int r = e / 65;
        int c = e - r * 65;
        int iy = iy0 + r;
        int gx = gx0 + c;
        int v = 0;
        if ((unsigned)iy < (unsigned)HH && (unsigned)gx < (unsigned)WW)
            v = gb[iy * WW + gx];
        sg[r * 66 + c] = v;
    }
    __syncthreads();

    int lc = 2 * p;             // local col base; window cols lc..lc+2

    // 1) read 15 window indices (5 rows x 3 cols) from LDS
    int v[15];
#pragma unroll
    for (int r = 0; r < 5; ++r)
#pragma unroll
        for (int dx = 0; dx < 3; ++dx)
            v[r * 3 + dx] = sg[r * 66 + lc + dx];

    // 2) issue all 15 loads unconditionally (empty -> row 0, broadcast)
    float4 f[15];
#pragma unroll
    for (int k = 0; k < 15; ++k) {
        int r = v[k] - 1;
        r = r < 0 ? 0 : r;
        f[k] = feat[(size_t)r * 8 + cg];
    }

    // 3) mask empties to -inf, fmax-reduce into two accumulators
    const float NEG = -INFINITY;
    float4 acc0 = make_float4(NEG, NEG, NEG, NEG);   // rows 0..2
    float4 acc1 = make_float4(NEG, NEG, NEG, NEG);   // rows 2..4
#pragma unroll
    for (int k = 0; k < 15; ++k) {
        bool ok = v[k] != 0;
        float fx = ok ? f[k].x : NEG;
        float fy = ok ? f[k].y : NEG;
        float fz = ok ? f[k].z : NEG;
        float fw = ok ? f[k].w : NEG;
        if (k < 9) {            // rows 0,1,2
            acc0.x = fmaxf(acc0.x, fx);
            acc0.y = fmaxf(acc0.y, fy);
            acc0.z = fmaxf(acc0.z, fz);
            acc0.w = fmaxf(acc0.w, fw);
        }
        if (k >= 6) {           // rows 2,3,4
            acc1.x = fmaxf(acc1.x, fx);
            acc1.y = fmaxf(acc1.y, fy);
            acc1.z = fmaxf(acc1.z, fz);
            acc1.w = fmaxf(acc1.w, fw);
        }
    }

    acc0.x = isinf(acc0.x) ? 0.0f : acc0.x;
    acc0.y = isinf(acc0.y) ? 0.0f : acc0.y;
    acc0.z = isinf(acc0.z) ? 0.0f : acc0.z;
    acc0.w = isinf(acc0.w) ? 0.0f : acc0.w;
    acc1.x = isinf(acc1.x) ? 0.0f : acc1.x;
    acc1.y = isinf(acc1.y) ? 0.0f : acc1.y;
    acc1.z = isinf(acc1.z) ? 0.0f : acc1.z;
    acc1.w = isinf(acc1.w) ? 0.0f : acc1.w;

    int oy0  = 2 * t;
    size_t pos0 = ((size_t)(b * HO + oy0) * WO + ox_base + p);
    out[pos0 * 8 + cg]            = acc0;
    out[(pos0 + WO) * 8 + cg]     = acc1;
}

extern "C" void kernel_launch(void* const* d_in, const int* in_sizes, int n_in,
                              void* d_out, int out_size, void* d_ws, size_t ws_size,
                              hipStream_t stream) {
    const float* features = (const float*)d_in[0];   // N x 32 fp32
    const int*   coors    = (const int*)d_in[1];     // N x 3 int32
    int n = in_sizes[0] / CC;                        // N = 300000

    int* grid = (int*)d_ws;                          // B*H*W int32 = 4 MiB

    // 1) zero the index grid (0xAA-poisoned every timed call)
    {
        int n4 = (BB * HH * WW) / 4;                 // 262144 int4
        int blk = 256, grd = (n4 + blk - 1) / blk;
        fill_zero_kernel<<<grd, blk, 0, stream>>>((int4*)grid, n4);
    }
    // 2) scatter indices
    {
        int blk = 256, grd = (n + blk - 1) / blk;
        scatter_idx_kernel<<<grd, blk, 0, stream>>>(coors, grid, n);
    }
    // 3) pool: 4096 blocks (32 ox x 2 oy x 8 cg per block)
    {
        int grd = BB * (HO / 2) * (WO / 32);         // 4096
        pool_kernel<<<grd, 256, 0, stream>>>((const float4*)features, grid,
                                             (float4*)d_out);
    }
}

// Round 6
// 107.498 us; speedup vs baseline: 1.0237x; 1.0237x over previous
//
#include <hip/hip_runtime.h>
#include <math.h>

// Problem constants (from reference)
#define BB 4
#define HH 512
#define WW 512
#define CC 32      // channels; 32 floats = 8 float4 = 128 B per point
#define HO 256
#define WO 256

#define MAXOCC 192   // slots staged in LDS; overflow -> direct gather (avg occ ~93)

// Fill index grid with zeros (0 == empty). int4-vectorized.
__global__ void fill_zero_kernel(int4* __restrict__ g, int n4) {
    int i = blockIdx.x * blockDim.x + threadIdx.x;
    if (i < n4) g[i] = make_int4(0, 0, 0, 0);
}

// Scatter point index+1 into dense (B,H,W) int grid.
__global__ void scatter_idx_kernel(const int* __restrict__ coors,
                                   int* __restrict__ grid, int n) {
    int i = blockIdx.x * blockDim.x + threadIdx.x;
    if (i >= n) return;
    int b = coors[i * 3 + 0];
    int y = coors[i * 3 + 1];
    int x = coors[i * 3 + 2];
    grid[((size_t)b * HH + y) * WW + x] = i + 1;
}

// Block = 32 ox x 2 oy x 8 cg. Window = 5 rows x 65 cols.
// Pass A: load grid window + compact occupied cells to slots (LDS atomic).
// Pass B: stage each occupied feature row into LDS exactly once (swizzled).
// Pass C: 15 LDS window reads per thread, fmax-reduce, 2 coalesced stores.
__global__ void __launch_bounds__(256)
pool_kernel(const float4* __restrict__ feat,   // N x 8 float4
            const int* __restrict__ grid,      // B*H*W
            float4* __restrict__ out) {        // B*HO*WO x 8 float4
    // blockIdx.x: [b(2b) | t(7b) | ox_tile(3b)],  t = oy pair index 0..127
    int ox_base = (blockIdx.x & 7) * 32;
    int t       = (blockIdx.x >> 3) & 127;
    int b       = blockIdx.x >> 10;

    int tid = threadIdx.x;
    int cg  = tid & 7;          // channel group 0..7
    int p   = tid >> 3;         // local position 0..31

    int iy0 = 4 * t - 1;        // first of 5 input rows
    int gx0 = 2 * ox_base - 1;
    const int* gb = grid + (size_t)b * (HH * WW);

    __shared__ int    smap[5 * 65];        // 0=empty, s+1=slot, -(idx+1)=direct
    __shared__ int    srcidx[MAXOCC];      // slot -> point index
    __shared__ int    cnt;
    __shared__ float4 sfeat[MAXOCC * 8];   // swizzled: [s*8 + ((cg+s)&7)]

    if (tid == 0) cnt = 0;
    __syncthreads();

    // Pass A: fused grid load + compaction
    for (int e = tid; e < 5 * 65; e += 256) {
        int r = e / 65;
        int c = e - r * 65;
        int iy = iy0 + r;
        int gx = gx0 + c;
        int v = 0;
        if ((unsigned)iy < (unsigned)HH && (unsigned)gx < (unsigned)WW)
            v = gb[iy * WW + gx];
        int m = 0;
        if (v != 0) {
            int s = atomicAdd(&cnt, 1);
            if (s < MAXOCC) { srcidx[s] = v - 1; m = s + 1; }
            else            { m = -v; }        // overflow: direct gather
        }
        smap[e] = m;
    }
    __syncthreads();

    // Pass B: cooperative feature staging (8 lanes per row, 128 B contiguous)
    int total = cnt < MAXOCC ? cnt : MAXOCC;
    for (int s = (tid >> 3); s < total; s += 32) {
        sfeat[(s << 3) + ((cg + s) & 7)] = feat[(size_t)srcidx[s] * 8 + cg];
    }
    __syncthreads();

    // Pass C: window reduce from LDS
    int lc = 2 * p;             // window cols lc..lc+2
    int mm[15];
#pragma unroll
    for (int r = 0; r < 5; ++r)
#pragma unroll
        for (int dx = 0; dx < 3; ++dx)
            mm[r * 3 + dx] = smap[r * 65 + lc + dx];

    float4 f[15];
#pragma unroll
    for (int k = 0; k < 15; ++k) {
        int s = mm[k] > 0 ? mm[k] - 1 : 0;
        f[k] = sfeat[(s << 3) + ((cg + s) & 7)];
    }
    // rare overflow fixup (slots beyond MAXOCC): direct global gather
#pragma unroll
    for (int k = 0; k < 15; ++k) {
        if (mm[k] < 0) f[k] = feat[(size_t)(-mm[k] - 1) * 8 + cg];
    }

    const float NEG = -INFINITY;
    float4 acc0 = make_float4(NEG, NEG, NEG, NEG);   // rows 0..2
    float4 acc1 = make_float4(NEG, NEG, NEG, NEG);   // rows 2..4
#pragma unroll
    for (int k = 0; k < 15; ++k) {
        bool ok = mm[k] != 0;
        float fx = ok ? f[k].x : NEG;
        float fy = ok ? f[k].y : NEG;
        float fz = ok ? f[k].z : NEG;
        float fw = ok ? f[k].w : NEG;
        if (k < 9) {            // rows 0,1,2
            acc0.x = fmaxf(acc0.x, fx);
            acc0.y = fmaxf(acc0.y, fy);
            acc0.z = fmaxf(acc0.z, fz);
            acc0.w = fmaxf(acc0.w, fw);
        }
        if (k >= 6) {           // rows 2,3,4
            acc1.x = fmaxf(acc1.x, fx);
            acc1.y = fmaxf(acc1.y, fy);
            acc1.z = fmaxf(acc1.z, fz);
            acc1.w = fmaxf(acc1.w, fw);
        }
    }

    acc0.x = isinf(acc0.x) ? 0.0f : acc0.x;
    acc0.y = isinf(acc0.y) ? 0.0f : acc0.y;
    acc0.z = isinf(acc0.z) ? 0.0f : acc0.z;
    acc0.w = isinf(acc0.w) ? 0.0f : acc0.w;
    acc1.x = isinf(acc1.x) ? 0.0f : acc1.x;
    acc1.y = isinf(acc1.y) ? 0.0f : acc1.y;
    acc1.z = isinf(acc1.z) ? 0.0f : acc1.z;
    acc1.w = isinf(acc1.w) ? 0.0f : acc1.w;

    int oy0  = 2 * t;
    size_t pos0 = ((size_t)(b * HO + oy0) * WO + ox_base + p);
    out[pos0 * 8 + cg]        = acc0;
    out[(pos0 + WO) * 8 + cg] = acc1;
}

extern "C" void kernel_launch(void* const* d_in, const int* in_sizes, int n_in,
                              void* d_out, int out_size, void* d_ws, size_t ws_size,
                              hipStream_t stream) {
    const float* features = (const float*)d_in[0];   // N x 32 fp32
    const int*   coors    = (const int*)d_in[1];     // N x 3 int32
    int n = in_sizes[0] / CC;                        // N = 300000

    int* grid = (int*)d_ws;                          // B*H*W int32 = 4 MiB

    // 1) zero the index grid (0xAA-poisoned every timed call)
    {
        int n4 = (BB * HH * WW) / 4;                 // 262144 int4
        int blk = 256, grd = (n4 + blk - 1) / blk;
        fill_zero_kernel<<<grd, blk, 0, stream>>>((int4*)grid, n4);
    }
    // 2) scatter indices
    {
        int blk = 256, grd = (n + blk - 1) / blk;
        scatter_idx_kernel<<<grd, blk, 0, stream>>>(coors, grid, n);
    }
    // 3) pool: 4096 blocks (32 ox x 2 oy x 8 cg per block)
    {
        int grd = BB * (HO / 2) * (WO / 32);         // 4096
        pool_kernel<<<grd, 256, 0, stream>>>((const float4*)features, grid,
                                             (float4*)d_out);
    }
}